// Round 1
// baseline (9.711 us; speedup 1.0000x reference)
//
#include <hip/hip_runtime.h>

// Reference collapses analytically:
//   inputs == zeros  ->  hidden = tanh(b1)  ->  action a = W2 . tanh(b1) + b2  (one scalar)
//   curprice == 0    ->  cash stays 10000; shares += trunc(max(0,a)) per step (sell path dead)
//   out[i] = 10000 + TSTEPS * trunc(max(0,a)) * quotes[i, QLEN-1]
//
// Inputs (setup_inputs order): all_quotes[8192*4224] f32, W1[128*130] f32 (unused),
// b1[128] f32, W2[128] f32, b2[1] f32. Output: f32[8192].

#define BATCH   8192
#define NQ      128
#define QLEN    4224
#define TSTEPS  (QLEN - NQ)  // 4096

__global__ __launch_bounds__(256) void trading_closed_form(
    const float* __restrict__ quotes,
    const float* __restrict__ b1,
    const float* __restrict__ W2,
    const float* __restrict__ b2,
    float* __restrict__ out)
{
    __shared__ float terms[NQ];
    __shared__ float s_scale;

    const int tid = threadIdx.x;

    // Per-block redundant computation of the scalar action (128 tanh — negligible).
    if (tid < NQ) {
        terms[tid] = W2[tid] * tanhf(b1[tid]);
    }
    __syncthreads();
    if (tid == 0) {
        float a = b2[0];
        #pragma unroll
        for (int j = 0; j < NQ; ++j) a += terms[j];
        // buy per step: trunc(max(0,a)) as int32 -> integer-valued float k.
        // shares_final = TSTEPS * k (int32 arithmetic in ref; exact in f32 here
        // since k is tiny — a is O(0.05) by construction).
        float k = truncf(fmaxf(0.0f, a));
        s_scale = (float)TSTEPS * k;
    }
    __syncthreads();
    const float scale = s_scale;

    const int i = blockIdx.x * blockDim.x + tid;
    if (i < BATCH) {
        const float last = quotes[(size_t)i * QLEN + (QLEN - 1)];
        out[i] = 10000.0f + scale * last;
    }
}

extern "C" void kernel_launch(void* const* d_in, const int* in_sizes, int n_in,
                              void* d_out, int out_size, void* d_ws, size_t ws_size,
                              hipStream_t stream)
{
    const float* quotes = (const float*)d_in[0];
    // d_in[1] is W1 (unused: inputs are all-zero so W1 contributes nothing)
    const float* b1 = (const float*)d_in[2];
    const float* W2 = (const float*)d_in[3];
    const float* b2 = (const float*)d_in[4];
    float* out = (float*)d_out;

    const int block = 256;
    const int grid = (BATCH + block - 1) / block;  // 32 blocks
    trading_closed_form<<<grid, block, 0, stream>>>(quotes, b1, W2, b2, out);
}

// Round 2
// 9.407 us; speedup vs baseline: 1.0323x; 1.0323x over previous
//
#include <hip/hip_runtime.h>

// Reference collapses analytically:
//   inputs == zeros  ->  hidden = tanh(b1)  ->  action a = W2 . tanh(b1) + b2  (one scalar)
//   curprice == 0    ->  cash stays 10000; shares += trunc(max(0,a)) per step (sell path dead)
//   out[i] = 10000 + TSTEPS * trunc(max(0,a)) * quotes[i, QLEN-1]
//
// This round: single-wave blocks, quote load issued FIRST (overlaps scalar math),
// wave-parallel shuffle reduction (no LDS, no __syncthreads, no serial 128-add).

#define BATCH   8192
#define NQ      128
#define QLEN    4224
#define TSTEPS  (QLEN - NQ)  // 4096

__global__ __launch_bounds__(64) void trading_closed_form(
    const float* __restrict__ quotes,
    const float* __restrict__ b1,
    const float* __restrict__ W2,
    const float* __restrict__ b2,
    float* __restrict__ out)
{
    const int lane = threadIdx.x;                 // 0..63, one wave per block
    const int i = blockIdx.x * 64 + lane;         // batch index

    // Issue the strided global load immediately; compiler places s_waitcnt
    // right before the store, so the ~900-cycle miss latency hides under
    // the tanh/reduction work below.
    const float last = quotes[(size_t)i * QLEN + (QLEN - 1)];

    // Each lane computes 2 of the 128 terms (broadcast loads, L2-resident).
    float part = W2[lane] * tanhf(b1[lane])
               + W2[lane + 64] * tanhf(b1[lane + 64]);

    // 64-lane butterfly reduction — 6 shuffles, every lane ends with the sum.
    #pragma unroll
    for (int off = 32; off >= 1; off >>= 1)
        part += __shfl_xor(part, off, 64);

    const float a = part + b2[0];
    const float scale = (float)TSTEPS * truncf(fmaxf(0.0f, a));

    out[i] = 10000.0f + scale * last;
}

extern "C" void kernel_launch(void* const* d_in, const int* in_sizes, int n_in,
                              void* d_out, int out_size, void* d_ws, size_t ws_size,
                              hipStream_t stream)
{
    const float* quotes = (const float*)d_in[0];
    // d_in[1] is W1 (unused: inputs are all-zero so W1 contributes nothing)
    const float* b1 = (const float*)d_in[2];
    const float* W2 = (const float*)d_in[3];
    const float* b2 = (const float*)d_in[4];
    float* out = (float*)d_out;

    trading_closed_form<<<BATCH / 64, 64, 0, stream>>>(quotes, b1, W2, b2, out);
}